// Round 1
// baseline (267.132 us; speedup 1.0000x reference)
//
#include <hip/hip_runtime.h>
#include <math.h>

#define NQ   10880
#define TOK  5440

// ---------------------------------------------------------------------------
// Generic fp32 GEMM: C[M x ldc (+ccol0)] = A[M x 256] @ W[256 x N] + bias[N]
// M fixed = 10880 (170 blocks of 64 rows). BM=BN=64, BK=16, 256 thr, 4x4 micro.
// gather=1: A rows are gathered from feature_maps (valid tokens only).
// ---------------------------------------------------------------------------
__global__ __launch_bounds__(256) void gemm256_k(
    const float* __restrict__ A, const float* __restrict__ W,
    const float* __restrict__ bias, float* __restrict__ C,
    int N, int ldc, int ccol0, int gather, const float* __restrict__ fm)
{
    __shared__ float As[16][64];
    __shared__ float Bs[16][64];
    __shared__ const float* rowp[64];
    const int tid = threadIdx.x;
    const int bm = blockIdx.x, bn = blockIdx.y;

    if (tid < 64) {
        int r = bm * 64 + tid;
        const float* p;
        if (gather) {
            int b = r / TOK;
            int t = r - b * TOK;
            int l, hh, ww;
            if (t < 4096)      { l = 0; hh = t >> 6; ww = t & 63; }
            else if (t < 5120) { int i = t - 4096; l = 1; hh = i >> 5; ww = i & 31; }
            else if (t < 5376) { int i = t - 5120; l = 2; hh = i >> 4; ww = i & 15; }
            else               { int i = t - 5376; l = 3; hh = i >> 3; ww = i & 7; }
            // feature_maps layout: (B, 64, 64, 4, 256)
            p = fm + ((size_t)((((b * 64 + hh) * 64 + ww) * 4) + l) << 8);
        } else {
            p = A + (size_t)r * 256;
        }
        rowp[tid] = p;
    }
    __syncthreads();

    const int tx = tid & 15, ty = tid >> 4;
    const int arow = tid >> 2, akg = (tid & 3) << 2;
    const int bkk = tid >> 4, bnn = (tid & 15) << 2;
    const float* myrow = rowp[arow];
    const float* wptr  = W + (size_t)bkk * N + bn * 64 + bnn;

    float acc[4][4] = {};
    for (int k0 = 0; k0 < 256; k0 += 16) {
        float4 av = *(const float4*)(myrow + k0 + akg);
        float4 bv = *(const float4*)(wptr + (size_t)k0 * N);
        __syncthreads();
        As[akg + 0][arow] = av.x;
        As[akg + 1][arow] = av.y;
        As[akg + 2][arow] = av.z;
        As[akg + 3][arow] = av.w;
        *(float4*)&Bs[bkk][bnn] = bv;
        __syncthreads();
#pragma unroll
        for (int k = 0; k < 16; ++k) {
            float4 a4 = *(const float4*)&As[k][ty << 2];
            float4 b4 = *(const float4*)&Bs[k][tx << 2];
            float aa[4] = {a4.x, a4.y, a4.z, a4.w};
            float bb[4] = {b4.x, b4.y, b4.z, b4.w};
#pragma unroll
            for (int i = 0; i < 4; ++i)
#pragma unroll
                for (int j = 0; j < 4; ++j)
                    acc[i][j] = fmaf(aa[i], bb[j], acc[i][j]);
        }
    }

    const int col0 = bn * 64 + (tx << 2);
    float4 b4 = *(const float4*)(bias + col0);
    float bb[4] = {b4.x, b4.y, b4.z, b4.w};
#pragma unroll
    for (int i = 0; i < 4; ++i) {
        int r = bm * 64 + (ty << 2) + i;
        float4 o;
        o.x = acc[i][0] + bb[0];
        o.y = acc[i][1] + bb[1];
        o.z = acc[i][2] + bb[2];
        o.w = acc[i][3] + bb[3];
        *(float4*)(C + (size_t)r * ldc + ccol0 + col0) = o;
    }
}

// ---------------------------------------------------------------------------
// Sampling: per query block (256 thr: h = tid/32, d = tid%32).
// Reads offattn row (256 off + 128 attn logits), does per-head softmax over
// the 16 (p,l) logits, bilinear-gathers compact values, accumulates qout.
// ---------------------------------------------------------------------------
__global__ __launch_bounds__(256) void sample_k(
    const float* __restrict__ offattn,  // NQ x 384
    const float* __restrict__ values,   // (2*TOK) x 256 compact (level-major)
    const float* __restrict__ qpos,     // NQ x 2
    const int*   __restrict__ qlevel,   // NQ
    float* __restrict__ qout)           // NQ x 256
{
    const int q = blockIdx.x;
    const int tid = threadIdx.x;
    const int h = tid >> 5, d = tid & 31;

    __shared__ float sOff[256];
    __shared__ float sAtt[128];

    const float* row = offattn + (size_t)q * 384;
    sOff[tid] = row[tid];
    if (tid < 128) sAtt[tid] = row[256 + tid];
    __syncthreads();

    if (tid < 8) {
        // softmax over 16 entries (stride 8) for head tid
        float m = -1e30f;
#pragma unroll
        for (int j = 0; j < 16; ++j) m = fmaxf(m, sAtt[j * 8 + tid]);
        float e[16];
        float s = 0.f;
#pragma unroll
        for (int j = 0; j < 16; ++j) { e[j] = __expf(sAtt[j * 8 + tid] - m); s += e[j]; }
        float inv = 1.0f / s;
#pragma unroll
        for (int j = 0; j < 16; ++j) sAtt[j * 8 + tid] = e[j] * inv;
    }
    __syncthreads();

    const int b = q / TOK;
    const float ph = qpos[q * 2 + 0];
    const float pw = qpos[q * 2 + 1];
    const int ql = qlevel[q];
    const int HS[4]    = {64, 32, 16, 8};
    const int LBASE[4] = {0, 4096, 5120, 5376};
    const float invsh = 1.0f / (float)HS[ql];
    const float nh = ph * invsh;
    const float nw = pw * invsh;

    const float* vb = values + ((size_t)b * TOK) * 256 + h * 32 + d;
    float acc = 0.f;

#pragma unroll
    for (int l = 0; l < 4; ++l) {
        const int Hl = HS[l];
        const float Hlf = (float)Hl;
        const float sh = nh * Hlf;
        const float sw = nw * Hlf;
        const float* vlb = vb + (size_t)LBASE[l] * 256;
#pragma unroll
        for (int p = 0; p < 4; ++p) {
            const int c = (p * 4 + l) * 8 + h;
            const float aw = sAtt[c];
            float lh = sh + sOff[c * 2 + 0];
            float lw = sw + sOff[c * 2 + 1];
            lh = fminf(fmaxf(lh, 0.f), Hlf);
            lw = fminf(fmaxf(lw, 0.f), Hlf);
            const float fh0 = floorf(lh), fw0 = floorf(lw);
            const int h0 = (int)fh0, w0 = (int)fw0;
            const float fh = lh - fh0, fw = lw - fw0;
            float w00 = (1.f - fh) * (1.f - fw);
            float w01 = (1.f - fh) * fw;
            float w10 = fh * (1.f - fw);
            float w11 = fh * fw;
            const float okh0 = (h0 < Hl)     ? 1.f : 0.f;
            const float okh1 = (h0 + 1 < Hl) ? 1.f : 0.f;
            const float okw0 = (w0 < Hl)     ? 1.f : 0.f;
            const float okw1 = (w0 + 1 < Hl) ? 1.f : 0.f;
            w00 *= okh0 * okw0;
            w01 *= okh0 * okw1;
            w10 *= okh1 * okw0;
            w11 *= okh1 * okw1;
            const int h0c = min(h0, Hl - 1), h1c = min(h0 + 1, Hl - 1);
            const int w0c = min(w0, Hl - 1), w1c = min(w0 + 1, Hl - 1);
            const float v00 = vlb[(size_t)(h0c * Hl + w0c) * 256];
            const float v01 = vlb[(size_t)(h0c * Hl + w1c) * 256];
            const float v10 = vlb[(size_t)(h1c * Hl + w0c) * 256];
            const float v11 = vlb[(size_t)(h1c * Hl + w1c) * 256];
            acc += aw * (w00 * v00 + w01 * v01 + w10 * v10 + w11 * v11);
        }
    }
    qout[(size_t)q * 256 + tid] = acc;
}

// ---------------------------------------------------------------------------
extern "C" void kernel_launch(void* const* d_in, const int* in_sizes, int n_in,
                              void* d_out, int out_size, void* d_ws, size_t ws_size,
                              hipStream_t stream)
{
    const float* query  = (const float*)d_in[0];
    const float* qpos   = (const float*)d_in[1];
    // d_in[2]: query_batch_offsets (fixed [0,5440,10880] - hardcoded)
    const float* fm     = (const float*)d_in[3];
    // d_in[4]: level_spatial_shapes (fixed - hardcoded)
    const int*   qlvl   = (const int*)d_in[5];
    const float* W_off  = (const float*)d_in[6];
    const float* b_off  = (const float*)d_in[7];
    const float* W_attn = (const float*)d_in[8];
    const float* b_attn = (const float*)d_in[9];
    const float* W_val  = (const float*)d_in[10];
    const float* b_val  = (const float*)d_in[11];
    const float* W_out  = (const float*)d_in[12];
    const float* b_out  = (const float*)d_in[13];
    float* out = (float*)d_out;

    float* values  = (float*)d_ws;                    // NQ*256 fp32
    float* offattn = values + (size_t)NQ * 256;       // NQ*384 fp32
    float* qout    = offattn + (size_t)NQ * 384;      // NQ*256 fp32

    dim3 blk(256);
    // values = gathered(feature_maps) @ W_val + b_val  (compact, valid rows only)
    gemm256_k<<<dim3(170, 4), blk, 0, stream>>>(nullptr, W_val, b_val, values,
                                                256, 256, 0, 1, fm);
    // off = query @ W_off + b_off   -> offattn[:, 0:256]
    gemm256_k<<<dim3(170, 4), blk, 0, stream>>>(query, W_off, b_off, offattn,
                                                256, 384, 0, 0, nullptr);
    // attn logits = query @ W_attn + b_attn -> offattn[:, 256:384]
    gemm256_k<<<dim3(170, 2), blk, 0, stream>>>(query, W_attn, b_attn, offattn,
                                                128, 384, 256, 0, nullptr);
    // softmax + bilinear sampling + head-weighted accumulate
    sample_k<<<dim3(NQ), blk, 0, stream>>>(offattn, values, qpos, qlvl, qout);
    // out = qout @ W_out + b_out
    gemm256_k<<<dim3(170, 4), blk, 0, stream>>>(qout, W_out, b_out, out,
                                                256, 256, 0, 0, nullptr);
}

// Round 2
// 246.646 us; speedup vs baseline: 1.0831x; 1.0831x over previous
//
#include <hip/hip_runtime.h>
#include <math.h>

#define NQ   10880
#define TOK  5440

// ---------------------------------------------------------------------------
// fp32 GEMM: C[M x ldc (+ccol0)] = A[M x 256] @ W[256 x N] + bias[N]
// BM=128, BN=64, BK=16, 256 thr, 8x4 micro. M=10880=85*128 exactly.
// gather=1: A rows gathered from feature_maps (valid tokens only).
// ---------------------------------------------------------------------------
__global__ __launch_bounds__(256) void gemm256_k(
    const float* __restrict__ A, const float* __restrict__ W,
    const float* __restrict__ bias, float* __restrict__ C,
    int N, int ldc, int ccol0, int gather, const float* __restrict__ fm)
{
    __shared__ float As[16][128];
    __shared__ float Bs[16][64];
    __shared__ const float* rowp[128];
    const int tid = threadIdx.x;
    const int bm = blockIdx.x, bn = blockIdx.y;

    if (tid < 128) {
        int r = bm * 128 + tid;
        const float* p;
        if (gather) {
            int b = r / TOK;
            int t = r - b * TOK;
            int l, hh, ww;
            if (t < 4096)      { l = 0; hh = t >> 6; ww = t & 63; }
            else if (t < 5120) { int i = t - 4096; l = 1; hh = i >> 5; ww = i & 31; }
            else if (t < 5376) { int i = t - 5120; l = 2; hh = i >> 4; ww = i & 15; }
            else               { int i = t - 5376; l = 3; hh = i >> 3; ww = i & 7; }
            // feature_maps layout: (B, 64, 64, 4, 256)
            p = fm + ((size_t)((((b * 64 + hh) * 64 + ww) * 4) + l) << 8);
        } else {
            p = A + (size_t)r * 256;
        }
        rowp[tid] = p;
    }
    __syncthreads();

    const int arow = tid >> 1;            // 0..127
    const int akg  = (tid & 1) * 8;       // 0 or 8
    const int bk   = tid >> 4;            // 0..15
    const int bn4  = (tid & 15) << 2;
    const int tx   = tid & 15;            // 4 cols each
    const int ty   = tid >> 4;            // 8 rows each
    const float* myrow = rowp[arow];
    const float* wptr  = W + (size_t)bk * N + bn * 64 + bn4;

    float acc[8][4] = {};
    for (int k0 = 0; k0 < 256; k0 += 16) {
        float4 a0 = *(const float4*)(myrow + k0 + akg);
        float4 a1 = *(const float4*)(myrow + k0 + akg + 4);
        float4 bv = *(const float4*)(wptr + (size_t)k0 * N);
        __syncthreads();
        As[akg + 0][arow] = a0.x;
        As[akg + 1][arow] = a0.y;
        As[akg + 2][arow] = a0.z;
        As[akg + 3][arow] = a0.w;
        As[akg + 4][arow] = a1.x;
        As[akg + 5][arow] = a1.y;
        As[akg + 6][arow] = a1.z;
        As[akg + 7][arow] = a1.w;
        *(float4*)&Bs[bk][bn4] = bv;
        __syncthreads();
#pragma unroll
        for (int k = 0; k < 16; ++k) {
            float4 aA = *(const float4*)&As[k][ty << 3];
            float4 aB = *(const float4*)&As[k][(ty << 3) + 4];
            float4 b4 = *(const float4*)&Bs[k][tx << 2];
            float aa[8] = {aA.x, aA.y, aA.z, aA.w, aB.x, aB.y, aB.z, aB.w};
            float bb[4] = {b4.x, b4.y, b4.z, b4.w};
#pragma unroll
            for (int i = 0; i < 8; ++i)
#pragma unroll
                for (int j = 0; j < 4; ++j)
                    acc[i][j] = fmaf(aa[i], bb[j], acc[i][j]);
        }
    }

    const int col = bn * 64 + (tx << 2);
    float4 bv4 = *(const float4*)(bias + col);
#pragma unroll
    for (int i = 0; i < 8; ++i) {
        int r = bm * 128 + (ty << 3) + i;
        float4 o;
        o.x = acc[i][0] + bv4.x;
        o.y = acc[i][1] + bv4.y;
        o.z = acc[i][2] + bv4.z;
        o.w = acc[i][3] + bv4.w;
        *(float4*)(C + (size_t)r * ldc + ccol0 + col) = o;
    }
}

// ---------------------------------------------------------------------------
// Sampling: 4 queries / 256-thread block.
// Stage 1: stage offattn rows (4x384) in LDS; 32 threads do per-(q,h) softmax.
// Stage 2: 512 (q,p,l,h) sets -> precompute 4 attn-folded bilinear weights +
//          4 corner element-offsets into LDS (computed ONCE, not 32x).
// Stage 3: 64 threads/query (h x float4-group): 2 LDS b128 + 4 global float4
//          + 16 FMA per point.
// ---------------------------------------------------------------------------
__global__ __launch_bounds__(256) void sample_k(
    const float* __restrict__ offattn,  // NQ x 384 (256 off | 128 attn)
    const float* __restrict__ values,   // (2*TOK) x 256 compact (level-major)
    const float* __restrict__ qpos,     // NQ x 2
    const int*   __restrict__ qlevel,   // NQ
    float* __restrict__ qout)           // NQ x 256
{
    __shared__ float  sRow[4][384];
    __shared__ float4 sW[4][128];
    __shared__ int4   sIdx[4][128];

    const int tid = threadIdx.x;
    const int qbase = blockIdx.x << 2;

    // ---- stage 1: load offattn rows ----
    {
        const float* rb = offattn + (size_t)qbase * 384;
        float* sf = (float*)sRow;
#pragma unroll
        for (int i = 0; i < 6; ++i) sf[tid + i * 256] = rb[tid + i * 256];
    }
    __syncthreads();

    // ---- softmax per (q,h): 32 threads ----
    if (tid < 32) {
        const int qn = tid >> 3, h = tid & 7;
        float m = -1e30f;
#pragma unroll
        for (int j = 0; j < 16; ++j) m = fmaxf(m, sRow[qn][256 + j * 8 + h]);
        float e[16], s = 0.f;
#pragma unroll
        for (int j = 0; j < 16; ++j) { e[j] = __expf(sRow[qn][256 + j * 8 + h] - m); s += e[j]; }
        float inv = 1.0f / s;
#pragma unroll
        for (int j = 0; j < 16; ++j) sRow[qn][256 + j * 8 + h] = e[j] * inv;
    }
    __syncthreads();

    // ---- stage 2: precompute 512 weight/index sets (2 per thread) ----
    const int LBASE[4] = {0, 4096, 5120, 5376};
#pragma unroll
    for (int ss = 0; ss < 2; ++ss) {
        const int s  = tid + ss * 256;
        const int qn = s >> 7;
        const int c  = s & 127;
        const int h  = c & 7;
        const int pl = c >> 3;
        const int l  = pl & 3;
        const int q  = qbase + qn;
        const int b  = (q >= TOK) ? 1 : 0;
        const float ph = qpos[2 * q], pw = qpos[2 * q + 1];
        const int ql = qlevel[q];
        const float invq = 1.0f / (float)(64 >> ql);
        const int Hl = 64 >> l;
        const float Hlf = (float)Hl;
        const float sc = invq * Hlf;
        float lh = ph * sc + sRow[qn][2 * c];
        float lw = pw * sc + sRow[qn][2 * c + 1];
        const float aw = sRow[qn][256 + c];
        lh = fminf(fmaxf(lh, 0.f), Hlf);
        lw = fminf(fmaxf(lw, 0.f), Hlf);
        const float fh0 = floorf(lh), fw0 = floorf(lw);
        const int h0 = (int)fh0, w0 = (int)fw0;
        const float fh = lh - fh0, fw = lw - fw0;
        float w00 = (1.f - fh) * (1.f - fw);
        float w01 = (1.f - fh) * fw;
        float w10 = fh * (1.f - fw);
        float w11 = fh * fw;
        if (h0     >= Hl) { w00 = 0.f; w01 = 0.f; }
        if (h0 + 1 >= Hl) { w10 = 0.f; w11 = 0.f; }
        if (w0     >= Hl) { w00 = 0.f; w10 = 0.f; }
        if (w0 + 1 >= Hl) { w01 = 0.f; w11 = 0.f; }
        const int h0c = min(h0, Hl - 1), h1c = min(h0 + 1, Hl - 1);
        const int w0c = min(w0, Hl - 1), w1c = min(w0 + 1, Hl - 1);
        const int base = b * TOK + LBASE[l];
        sW[qn][c]   = make_float4(aw * w00, aw * w01, aw * w10, aw * w11);
        sIdx[qn][c] = make_int4((base + h0c * Hl + w0c) << 8,
                                (base + h0c * Hl + w1c) << 8,
                                (base + h1c * Hl + w0c) << 8,
                                (base + h1c * Hl + w1c) << 8);
    }
    __syncthreads();

    // ---- stage 3: gather + accumulate ----
    const int qn = tid >> 6;
    const int t  = tid & 63;
    const int h  = t >> 3;
    const int dg = t & 7;
    const float* vb = values + h * 32 + (dg << 2);
    float4 acc = {0.f, 0.f, 0.f, 0.f};
#pragma unroll
    for (int pl = 0; pl < 16; ++pl) {
        const int c = pl * 8 + h;
        const float4 w = sW[qn][c];
        const int4  id = sIdx[qn][c];
        const float4 v00 = *(const float4*)(vb + id.x);
        const float4 v01 = *(const float4*)(vb + id.y);
        const float4 v10 = *(const float4*)(vb + id.z);
        const float4 v11 = *(const float4*)(vb + id.w);
        acc.x = fmaf(w.x, v00.x, acc.x);
        acc.y = fmaf(w.x, v00.y, acc.y);
        acc.z = fmaf(w.x, v00.z, acc.z);
        acc.w = fmaf(w.x, v00.w, acc.w);
        acc.x = fmaf(w.y, v01.x, acc.x);
        acc.y = fmaf(w.y, v01.y, acc.y);
        acc.z = fmaf(w.y, v01.z, acc.z);
        acc.w = fmaf(w.y, v01.w, acc.w);
        acc.x = fmaf(w.z, v10.x, acc.x);
        acc.y = fmaf(w.z, v10.y, acc.y);
        acc.z = fmaf(w.z, v10.z, acc.z);
        acc.w = fmaf(w.z, v10.w, acc.w);
        acc.x = fmaf(w.w, v11.x, acc.x);
        acc.y = fmaf(w.w, v11.y, acc.y);
        acc.z = fmaf(w.w, v11.z, acc.z);
        acc.w = fmaf(w.w, v11.w, acc.w);
    }
    const int q = qbase + qn;
    *(float4*)(qout + (size_t)q * 256 + h * 32 + (dg << 2)) = acc;
}

// ---------------------------------------------------------------------------
extern "C" void kernel_launch(void* const* d_in, const int* in_sizes, int n_in,
                              void* d_out, int out_size, void* d_ws, size_t ws_size,
                              hipStream_t stream)
{
    const float* query  = (const float*)d_in[0];
    const float* qpos   = (const float*)d_in[1];
    const float* fm     = (const float*)d_in[3];
    const int*   qlvl   = (const int*)d_in[5];
    const float* W_off  = (const float*)d_in[6];
    const float* b_off  = (const float*)d_in[7];
    const float* W_attn = (const float*)d_in[8];
    const float* b_attn = (const float*)d_in[9];
    const float* W_val  = (const float*)d_in[10];
    const float* b_val  = (const float*)d_in[11];
    const float* W_out  = (const float*)d_in[12];
    const float* b_out  = (const float*)d_in[13];
    float* out = (float*)d_out;

    float* values  = (float*)d_ws;                    // NQ*256 fp32
    float* offattn = values + (size_t)NQ * 256;       // NQ*384 fp32
    float* qout    = offattn + (size_t)NQ * 384;      // NQ*256 fp32

    dim3 blk(256);
    gemm256_k<<<dim3(85, 4), blk, 0, stream>>>(nullptr, W_val, b_val, values,
                                               256, 256, 0, 1, fm);
    gemm256_k<<<dim3(85, 4), blk, 0, stream>>>(query, W_off, b_off, offattn,
                                               256, 384, 0, 0, nullptr);
    gemm256_k<<<dim3(85, 2), blk, 0, stream>>>(query, W_attn, b_attn, offattn,
                                               128, 384, 256, 0, nullptr);
    sample_k<<<dim3(NQ / 4), blk, 0, stream>>>(offattn, values, qpos, qlvl, qout);
    gemm256_k<<<dim3(85, 4), blk, 0, stream>>>(qout, W_out, b_out, out,
                                               256, 256, 0, 0, nullptr);
}

// Round 3
// 165.114 us; speedup vs baseline: 1.6179x; 1.4938x over previous
//
#include <hip/hip_runtime.h>
#include <math.h>

#define NQ   10880
#define TOK  5440

typedef short s16x8 __attribute__((ext_vector_type(8)));
typedef float f32x4 __attribute__((ext_vector_type(4)));

__device__ __forceinline__ float bf2f(unsigned short u) {
    return __uint_as_float(((unsigned int)u) << 16);
}
__device__ __forceinline__ unsigned short f2bf(float f) {
    unsigned int u = __float_as_uint(f);
    u += 0x7FFFu + ((u >> 16) & 1u);
    return (unsigned short)(u >> 16);
}

// ---------------------------------------------------------------------------
// bf16 MFMA GEMM: C[M x ldc (+bn*64)] = A[M x 256] @ W[256 x N] + bias[N]
// BM=BN=64, BK=64, 256 thr (4 waves), each wave computes a 32x32 quadrant
// with 2x2 grid of 16x16x32 mfma. fp32->bf16 conversion fused into staging.
// A source: fp32 rows (A), bf16 rows (Abf), or gathered fm rows (gather=1).
// W select per block: cols [0,N1) from W1/bias1, cols [N1,N1+N2) from W2/bias2.
// ---------------------------------------------------------------------------
__global__ __launch_bounds__(256) void gemm_bf16_k(
    const float* __restrict__ A, const unsigned short* __restrict__ Abf,
    int gather, const float* __restrict__ fm,
    const float* __restrict__ W1, const float* __restrict__ bias1, int N1,
    const float* __restrict__ W2, const float* __restrict__ bias2, int N2,
    void* __restrict__ Cv, int ldc, int cbf)
{
    __shared__ unsigned short As[64][72];   // [m][k], 72-pad: 36-word stride
    __shared__ unsigned short Bs[64][72];   // [n][k]
    __shared__ const void* rowp[64];

    const int tid = threadIdx.x;
    const int bm = blockIdx.x, bn = blockIdx.y;
    const int n0 = bn * 64;

    const float* W; const float* bias; int ldw, wc;
    if (n0 < N1) { W = W1; bias = bias1; ldw = N1; wc = n0; }
    else         { W = W2; bias = bias2; ldw = N2; wc = n0 - N1; }

    if (tid < 64) {
        int r = bm * 64 + tid;
        const void* p;
        if (Abf) {
            p = Abf + (size_t)r * 256;
        } else if (gather) {
            int b = (r >= TOK) ? 1 : 0;
            int t = r - b * TOK;
            int l, hh, ww;
            if (t < 4096)      { l = 0; hh = t >> 6; ww = t & 63; }
            else if (t < 5120) { int i = t - 4096; l = 1; hh = i >> 5; ww = i & 31; }
            else if (t < 5376) { int i = t - 5120; l = 2; hh = i >> 4; ww = i & 15; }
            else               { int i = t - 5376; l = 3; hh = i >> 3; ww = i & 7; }
            p = fm + ((size_t)((((b * 64 + hh) * 64 + ww) * 4) + l) << 8);
        } else {
            p = A + (size_t)r * 256;
        }
        rowp[tid] = p;
    }

    const int ar  = tid >> 2;              // A stage: row 0..63
    const int ac  = (tid & 3) << 4;        // A stage: 16-elt k-chunk
    const int bnr = tid & 63;              // B stage: n row
    const int bkc = (tid >> 6) << 4;       // B stage: 16-elt k-chunk
    const int w = tid >> 6, lane = tid & 63;
    const int quad = lane >> 4, fl = lane & 15;
    const int quad8 = quad << 3;
    const int mW = (w >> 1) << 5, nW = (w & 1) << 5;
    const int abf_flag = (Abf != nullptr);

    f32x4 acc00 = {0.f, 0.f, 0.f, 0.f};
    f32x4 acc01 = acc00, acc10 = acc00, acc11 = acc00;

    __syncthreads();

    for (int k0 = 0; k0 < 256; k0 += 64) {
        union { unsigned short u[16]; uint4 q[2]; } abuf;
        if (abf_flag) {
            const unsigned short* s = (const unsigned short*)rowp[ar] + k0 + ac;
            abuf.q[0] = *(const uint4*)(s);
            abuf.q[1] = *(const uint4*)(s + 8);
        } else {
            const float* s = (const float*)rowp[ar] + k0 + ac;
            float4 f0 = *(const float4*)(s);
            float4 f1 = *(const float4*)(s + 4);
            float4 f2 = *(const float4*)(s + 8);
            float4 f3 = *(const float4*)(s + 12);
            abuf.u[0] = f2bf(f0.x);  abuf.u[1] = f2bf(f0.y);
            abuf.u[2] = f2bf(f0.z);  abuf.u[3] = f2bf(f0.w);
            abuf.u[4] = f2bf(f1.x);  abuf.u[5] = f2bf(f1.y);
            abuf.u[6] = f2bf(f1.z);  abuf.u[7] = f2bf(f1.w);
            abuf.u[8] = f2bf(f2.x);  abuf.u[9] = f2bf(f2.y);
            abuf.u[10] = f2bf(f2.z); abuf.u[11] = f2bf(f2.w);
            abuf.u[12] = f2bf(f3.x); abuf.u[13] = f2bf(f3.y);
            abuf.u[14] = f2bf(f3.z); abuf.u[15] = f2bf(f3.w);
        }
        union { unsigned short u[16]; uint4 q[2]; } bbuf;
        {
            const float* wp = W + (size_t)(k0 + bkc) * ldw + wc + bnr;
#pragma unroll
            for (int i = 0; i < 16; ++i) { bbuf.u[i] = f2bf(*wp); wp += ldw; }
        }
        __syncthreads();   // previous tile's frags consumed
        *(uint4*)&As[ar][ac]      = abuf.q[0];
        *(uint4*)&As[ar][ac + 8]  = abuf.q[1];
        *(uint4*)&Bs[bnr][bkc]     = bbuf.q[0];
        *(uint4*)&Bs[bnr][bkc + 8] = bbuf.q[1];
        __syncthreads();
#pragma unroll
        for (int ks = 0; ks < 64; ks += 32) {
            s16x8 a0 = *(const s16x8*)&As[mW + fl][ks + quad8];
            s16x8 a1 = *(const s16x8*)&As[mW + 16 + fl][ks + quad8];
            s16x8 b0 = *(const s16x8*)&Bs[nW + fl][ks + quad8];
            s16x8 b1 = *(const s16x8*)&Bs[nW + 16 + fl][ks + quad8];
            acc00 = __builtin_amdgcn_mfma_f32_16x16x32_bf16(a0, b0, acc00, 0, 0, 0);
            acc01 = __builtin_amdgcn_mfma_f32_16x16x32_bf16(a0, b1, acc01, 0, 0, 0);
            acc10 = __builtin_amdgcn_mfma_f32_16x16x32_bf16(a1, b0, acc10, 0, 0, 0);
            acc11 = __builtin_amdgcn_mfma_f32_16x16x32_bf16(a1, b1, acc11, 0, 0, 0);
        }
    }

    // epilogue: D[row=quad*4+r][col=fl] per 16x16 tile
    const float bias0 = bias[wc + nW + fl];
    const float bias1v = bias[wc + nW + 16 + fl];
    const int row_base = bm * 64 + mW + (quad << 2);
    const int col0 = n0 + nW + fl;
    float* Cf = (float*)Cv;
    unsigned short* Cb = (unsigned short*)Cv;
#pragma unroll
    for (int r = 0; r < 4; ++r) {
        const int r0 = row_base + r, r1 = row_base + 16 + r;
        const float v00 = acc00[r] + bias0, v01 = acc01[r] + bias1v;
        const float v10 = acc10[r] + bias0, v11 = acc11[r] + bias1v;
        if (cbf) {
            Cb[(size_t)r0 * ldc + col0]      = f2bf(v00);
            Cb[(size_t)r0 * ldc + col0 + 16] = f2bf(v01);
            Cb[(size_t)r1 * ldc + col0]      = f2bf(v10);
            Cb[(size_t)r1 * ldc + col0 + 16] = f2bf(v11);
        } else {
            Cf[(size_t)r0 * ldc + col0]      = v00;
            Cf[(size_t)r0 * ldc + col0 + 16] = v01;
            Cf[(size_t)r1 * ldc + col0]      = v10;
            Cf[(size_t)r1 * ldc + col0 + 16] = v11;
        }
    }
}

// ---------------------------------------------------------------------------
// Sampling: 4 queries / 256-thread block. values and qout are bf16.
// ---------------------------------------------------------------------------
__global__ __launch_bounds__(256) void sample_k(
    const float* __restrict__ offattn,          // NQ x 384 (256 off | 128 attn)
    const unsigned short* __restrict__ values,  // (2*TOK) x 256 bf16 compact
    const float* __restrict__ qpos,             // NQ x 2
    const int*   __restrict__ qlevel,           // NQ
    unsigned short* __restrict__ qout)          // NQ x 256 bf16
{
    __shared__ float  sRow[4][384];
    __shared__ float4 sW[4][128];
    __shared__ int4   sIdx[4][128];

    const int tid = threadIdx.x;
    const int qbase = blockIdx.x << 2;

    {
        const float* rb = offattn + (size_t)qbase * 384;
        float* sf = (float*)sRow;
#pragma unroll
        for (int i = 0; i < 6; ++i) sf[tid + i * 256] = rb[tid + i * 256];
    }
    __syncthreads();

    if (tid < 32) {
        const int qn = tid >> 3, h = tid & 7;
        float m = -1e30f;
#pragma unroll
        for (int j = 0; j < 16; ++j) m = fmaxf(m, sRow[qn][256 + j * 8 + h]);
        float e[16], s = 0.f;
#pragma unroll
        for (int j = 0; j < 16; ++j) { e[j] = __expf(sRow[qn][256 + j * 8 + h] - m); s += e[j]; }
        float inv = 1.0f / s;
#pragma unroll
        for (int j = 0; j < 16; ++j) sRow[qn][256 + j * 8 + h] = e[j] * inv;
    }
    __syncthreads();

    const int LBASE[4] = {0, 4096, 5120, 5376};
#pragma unroll
    for (int ss = 0; ss < 2; ++ss) {
        const int s  = tid + ss * 256;
        const int qn = s >> 7;
        const int c  = s & 127;
        const int pl = c >> 3;
        const int l  = pl & 3;
        const int q  = qbase + qn;
        const int b  = (q >= TOK) ? 1 : 0;
        const float ph = qpos[2 * q], pw = qpos[2 * q + 1];
        const int ql = qlevel[q];
        const float invq = 1.0f / (float)(64 >> ql);
        const int Hl = 64 >> l;
        const float Hlf = (float)Hl;
        const float sc = invq * Hlf;
        float lh = ph * sc + sRow[qn][2 * c];
        float lw = pw * sc + sRow[qn][2 * c + 1];
        const float aw = sRow[qn][256 + c];
        lh = fminf(fmaxf(lh, 0.f), Hlf);
        lw = fminf(fmaxf(lw, 0.f), Hlf);
        const float fh0 = floorf(lh), fw0 = floorf(lw);
        const int h0 = (int)fh0, w0 = (int)fw0;
        const float fh = lh - fh0, fw = lw - fw0;
        float w00 = (1.f - fh) * (1.f - fw);
        float w01 = (1.f - fh) * fw;
        float w10 = fh * (1.f - fw);
        float w11 = fh * fw;
        if (h0     >= Hl) { w00 = 0.f; w01 = 0.f; }
        if (h0 + 1 >= Hl) { w10 = 0.f; w11 = 0.f; }
        if (w0     >= Hl) { w00 = 0.f; w10 = 0.f; }
        if (w0 + 1 >= Hl) { w01 = 0.f; w11 = 0.f; }
        const int h0c = min(h0, Hl - 1), h1c = min(h0 + 1, Hl - 1);
        const int w0c = min(w0, Hl - 1), w1c = min(w0 + 1, Hl - 1);
        const int base = b * TOK + LBASE[l];
        sW[qn][c]   = make_float4(aw * w00, aw * w01, aw * w10, aw * w11);
        sIdx[qn][c] = make_int4((base + h0c * Hl + w0c) << 8,
                                (base + h0c * Hl + w1c) << 8,
                                (base + h1c * Hl + w0c) << 8,
                                (base + h1c * Hl + w1c) << 8);
    }
    __syncthreads();

    const int qn = tid >> 6;
    const int t  = tid & 63;
    const int h  = t >> 3;
    const int dg = t & 7;
    const unsigned short* vb = values + h * 32 + (dg << 2);
    float4 acc = {0.f, 0.f, 0.f, 0.f};
#pragma unroll
    for (int pl = 0; pl < 16; ++pl) {
        const int c = pl * 8 + h;
        const float4 wt = sW[qn][c];
        const int4  id = sIdx[qn][c];
        const ushort4 u00 = *(const ushort4*)(vb + id.x);
        const ushort4 u01 = *(const ushort4*)(vb + id.y);
        const ushort4 u10 = *(const ushort4*)(vb + id.z);
        const ushort4 u11 = *(const ushort4*)(vb + id.w);
        acc.x = fmaf(wt.x, bf2f(u00.x), acc.x);
        acc.y = fmaf(wt.x, bf2f(u00.y), acc.y);
        acc.z = fmaf(wt.x, bf2f(u00.z), acc.z);
        acc.w = fmaf(wt.x, bf2f(u00.w), acc.w);
        acc.x = fmaf(wt.y, bf2f(u01.x), acc.x);
        acc.y = fmaf(wt.y, bf2f(u01.y), acc.y);
        acc.z = fmaf(wt.y, bf2f(u01.z), acc.z);
        acc.w = fmaf(wt.y, bf2f(u01.w), acc.w);
        acc.x = fmaf(wt.z, bf2f(u10.x), acc.x);
        acc.y = fmaf(wt.z, bf2f(u10.y), acc.y);
        acc.z = fmaf(wt.z, bf2f(u10.z), acc.z);
        acc.w = fmaf(wt.z, bf2f(u10.w), acc.w);
        acc.x = fmaf(wt.w, bf2f(u11.x), acc.x);
        acc.y = fmaf(wt.w, bf2f(u11.y), acc.y);
        acc.z = fmaf(wt.w, bf2f(u11.z), acc.z);
        acc.w = fmaf(wt.w, bf2f(u11.w), acc.w);
    }
    const int q = qbase + qn;
    ushort4 o;
    o.x = f2bf(acc.x); o.y = f2bf(acc.y); o.z = f2bf(acc.z); o.w = f2bf(acc.w);
    *(ushort4*)(qout + (size_t)q * 256 + h * 32 + (dg << 2)) = o;
}

// ---------------------------------------------------------------------------
extern "C" void kernel_launch(void* const* d_in, const int* in_sizes, int n_in,
                              void* d_out, int out_size, void* d_ws, size_t ws_size,
                              hipStream_t stream)
{
    const float* query  = (const float*)d_in[0];
    const float* qpos   = (const float*)d_in[1];
    const float* fm     = (const float*)d_in[3];
    const int*   qlvl   = (const int*)d_in[5];
    const float* W_off  = (const float*)d_in[6];
    const float* b_off  = (const float*)d_in[7];
    const float* W_attn = (const float*)d_in[8];
    const float* b_attn = (const float*)d_in[9];
    const float* W_val  = (const float*)d_in[10];
    const float* b_val  = (const float*)d_in[11];
    const float* W_out  = (const float*)d_in[12];
    const float* b_out  = (const float*)d_in[13];
    float* out = (float*)d_out;

    unsigned short* values  = (unsigned short*)d_ws;                  // NQ*256 bf16
    float*          offattn = (float*)((char*)d_ws + (size_t)NQ * 256 * 2);
    unsigned short* qout    = (unsigned short*)((char*)offattn + (size_t)NQ * 384 * 4);

    dim3 blk(256);
    // values(bf16) = bf16(gather(fm)) @ bf16(W_val) + b_val
    gemm_bf16_k<<<dim3(170, 4), blk, 0, stream>>>(
        nullptr, nullptr, 1, fm, W_val, b_val, 256,
        nullptr, nullptr, 0, values, 256, 1);
    // offattn(fp32) = bf16(query) @ [W_off | W_attn] + [b_off | b_attn]
    gemm_bf16_k<<<dim3(170, 6), blk, 0, stream>>>(
        query, nullptr, 0, nullptr, W_off, b_off, 256,
        W_attn, b_attn, 128, offattn, 384, 0);
    // softmax + bilinear sampling (bf16 values) -> qout(bf16)
    sample_k<<<dim3(NQ / 4), blk, 0, stream>>>(offattn, values, qpos, qlvl, qout);
    // out(fp32) = qout(bf16) @ bf16(W_out) + b_out
    gemm_bf16_k<<<dim3(170, 4), blk, 0, stream>>>(
        nullptr, qout, 0, nullptr, W_out, b_out, 256,
        nullptr, nullptr, 0, out, 256, 0);
}

// Round 4
// 157.904 us; speedup vs baseline: 1.6917x; 1.0457x over previous
//
#include <hip/hip_runtime.h>
#include <math.h>

#define NQ   10880
#define TOK  5440

typedef short s16x8 __attribute__((ext_vector_type(8)));
typedef float f32x4 __attribute__((ext_vector_type(4)));

__device__ __forceinline__ float bf2f_lo(unsigned int u) {
    return __uint_as_float(u << 16);
}
__device__ __forceinline__ float bf2f_hi(unsigned int u) {
    return __uint_as_float(u & 0xFFFF0000u);
}
__device__ __forceinline__ unsigned short f2bf(float f) {
    unsigned int u = __float_as_uint(f);
    u += 0x7FFFu + ((u >> 16) & 1u);
    return (unsigned short)(u >> 16);
}
__device__ __forceinline__ unsigned int pack2(float a, float b) {
    return (unsigned int)f2bf(a) | ((unsigned int)f2bf(b) << 16);
}

// ---------------------------------------------------------------------------
// prep: query->bf16 (qbf), gather fm->bf16 compact (vsrc),
//       transpose+convert weights -> WtAll[896][256] bf16
//       (rows 0..255: W_val cols; 256..511: W_off; 512..639: W_attn;
//        640..895: W_out)
// ---------------------------------------------------------------------------
__global__ __launch_bounds__(256) void prep_k(
    const float* __restrict__ query, const float* __restrict__ fm,
    const float* __restrict__ W_val, const float* __restrict__ W_off,
    const float* __restrict__ W_attn, const float* __restrict__ W_out,
    unsigned short* __restrict__ qbf, unsigned short* __restrict__ vsrc,
    unsigned short* __restrict__ WtAll)
{
    const int blk = blockIdx.x;
    const int tid = threadIdx.x;

    if (blk < 2720) {
        // query -> qbf
        const int lin4 = blk * 256 + tid;
        float4 f = *(const float4*)(query + (size_t)lin4 * 4);
        uint2 o;
        o.x = pack2(f.x, f.y);
        o.y = pack2(f.z, f.w);
        *(uint2*)(qbf + (size_t)lin4 * 4) = o;
    } else if (blk < 5440) {
        // gather fm -> vsrc (compact token rows, level-major)
        const int lin4 = (blk - 2720) * 256 + tid;
        const int r = lin4 >> 6;
        const int c4 = (lin4 & 63) << 2;
        const int b = (r >= TOK) ? 1 : 0;
        const int t = r - b * TOK;
        int l, hh, ww;
        if (t < 4096)      { l = 0; hh = t >> 6; ww = t & 63; }
        else if (t < 5120) { int i = t - 4096; l = 1; hh = i >> 5; ww = i & 31; }
        else if (t < 5376) { int i = t - 5120; l = 2; hh = i >> 4; ww = i & 15; }
        else               { int i = t - 5376; l = 3; hh = i >> 3; ww = i & 7; }
        const float* p = fm + ((size_t)((((b * 64 + hh) * 64 + ww) * 4) + l) << 8) + c4;
        float4 f = *(const float4*)p;
        uint2 o;
        o.x = pack2(f.x, f.y);
        o.y = pack2(f.z, f.w);
        *(uint2*)(vsrc + (size_t)r * 256 + c4) = o;
    } else {
        // transpose weights: 56 blocks, each a 64(k) x 64(c) tile
        __shared__ unsigned short T[64][72];
        const int bt = blk - 5440;
        const int kt = bt & 3;          // k-tile (0..3)
        const int ct = bt >> 2;         // c-tile (0..13)
        const int c0 = ct * 64;
        const float* Wp; int ldw, cl0;
        if (c0 < 256)      { Wp = W_val;  ldw = 256; cl0 = c0; }
        else if (c0 < 512) { Wp = W_off;  ldw = 256; cl0 = c0 - 256; }
        else if (c0 < 640) { Wp = W_attn; ldw = 128; cl0 = c0 - 512; }
        else               { Wp = W_out;  ldw = 256; cl0 = c0 - 640; }

        const int kk = tid >> 2;
        const int cq = (tid & 3) << 4;
        const float* src = Wp + (size_t)(kt * 64 + kk) * ldw + cl0 + cq;
        float4 f0 = *(const float4*)(src);
        float4 f1 = *(const float4*)(src + 4);
        float4 f2 = *(const float4*)(src + 8);
        float4 f3 = *(const float4*)(src + 12);
        uint4 w0, w1;
        w0.x = pack2(f0.x, f0.y); w0.y = pack2(f0.z, f0.w);
        w0.z = pack2(f1.x, f1.y); w0.w = pack2(f1.z, f1.w);
        w1.x = pack2(f2.x, f2.y); w1.y = pack2(f2.z, f2.w);
        w1.z = pack2(f3.x, f3.y); w1.w = pack2(f3.z, f3.w);
        *(uint4*)&T[kk][cq]     = w0;
        *(uint4*)&T[kk][cq + 8] = w1;
        __syncthreads();
        const int cc = tid >> 2;
        const int kq = (tid & 3) << 4;
        union { unsigned short u[16]; uint4 q[2]; } ob;
#pragma unroll
        for (int j = 0; j < 16; ++j) ob.u[j] = T[kq + j][cc];
        unsigned short* dst = WtAll + (size_t)(c0 + cc) * 256 + kt * 64 + kq;
        *(uint4*)(dst)     = ob.q[0];
        *(uint4*)(dst + 8) = ob.q[1];
    }
}

// ---------------------------------------------------------------------------
// all-bf16 MFMA GEMM: C = A[M x 256] @ WtAll[wr0..wr0+128][256]^T + bias
// BM=BN=128, BK=64, 256 thr (4 waves), each wave 64x64 (4x4 of 16x16x32).
// mode 0: bn 0,1 -> values(bf16) from vsrc; bn 2..4 -> offattn(f32) from qbf.
// mode 1: bn 0,1 -> out(f32) from qout (A1).
// ---------------------------------------------------------------------------
__global__ __launch_bounds__(256) void gemm_bf16_k(
    const unsigned short* __restrict__ A1, const unsigned short* __restrict__ A2,
    const unsigned short* __restrict__ Wt,
    const float* __restrict__ bias1, const float* __restrict__ bias2,
    const float* __restrict__ bias3,
    void* __restrict__ C1, void* __restrict__ C2, int mode)
{
    __shared__ unsigned short As[128][72];
    __shared__ unsigned short Bs[128][72];

    const int tid = threadIdx.x;
    const int bm = blockIdx.x, bn = blockIdx.y;

    const unsigned short* A;
    const float* bias;
    void* Cp; int ldc, col0, cbf, wr0;
    if (mode == 0) {
        if (bn < 2) {
            A = A1; wr0 = bn * 128; bias = bias1 + bn * 128;
            Cp = C1; ldc = 256; col0 = bn * 128; cbf = 1;
        } else {
            A = A2; wr0 = bn * 128;
            bias = (bn < 4) ? bias2 + (bn - 2) * 128 : bias3;
            Cp = C2; ldc = 384; col0 = (bn - 2) * 128; cbf = 0;
        }
    } else {
        A = A1; wr0 = 640 + bn * 128; bias = bias1 + bn * 128;
        Cp = C1; ldc = 256; col0 = bn * 128; cbf = 0;
    }

    const int sr  = tid >> 1;            // staging row 0..127
    const int skc = (tid & 1) << 5;      // staging k-chunk (32 elts)
    const unsigned short* Ap = A  + (size_t)(bm * 128 + sr) * 256 + skc;
    const unsigned short* Bp = Wt + (size_t)(wr0 + sr) * 256 + skc;

    const int w = tid >> 6, lane = tid & 63;
    const int quad = lane >> 4, fl = lane & 15;
    const int quad8 = quad << 3;
    const int mW = (w >> 1) << 6, nW = (w & 1) << 6;

    f32x4 acc[4][4] = {};

    for (int k0 = 0; k0 < 256; k0 += 64) {
        uint4 av0 = *(const uint4*)(Ap + k0);
        uint4 av1 = *(const uint4*)(Ap + k0 + 8);
        uint4 av2 = *(const uint4*)(Ap + k0 + 16);
        uint4 av3 = *(const uint4*)(Ap + k0 + 24);
        uint4 bv0 = *(const uint4*)(Bp + k0);
        uint4 bv1 = *(const uint4*)(Bp + k0 + 8);
        uint4 bv2 = *(const uint4*)(Bp + k0 + 16);
        uint4 bv3 = *(const uint4*)(Bp + k0 + 24);
        __syncthreads();   // previous tile consumed
        *(uint4*)&As[sr][skc]      = av0;
        *(uint4*)&As[sr][skc + 8]  = av1;
        *(uint4*)&As[sr][skc + 16] = av2;
        *(uint4*)&As[sr][skc + 24] = av3;
        *(uint4*)&Bs[sr][skc]      = bv0;
        *(uint4*)&Bs[sr][skc + 8]  = bv1;
        *(uint4*)&Bs[sr][skc + 16] = bv2;
        *(uint4*)&Bs[sr][skc + 24] = bv3;
        __syncthreads();
#pragma unroll
        for (int ks = 0; ks < 64; ks += 32) {
            s16x8 af[4], bf[4];
#pragma unroll
            for (int i = 0; i < 4; ++i) {
                af[i] = *(const s16x8*)&As[mW + i * 16 + fl][ks + quad8];
                bf[i] = *(const s16x8*)&Bs[nW + i * 16 + fl][ks + quad8];
            }
#pragma unroll
            for (int i = 0; i < 4; ++i)
#pragma unroll
                for (int j = 0; j < 4; ++j)
                    acc[i][j] = __builtin_amdgcn_mfma_f32_16x16x32_bf16(
                        af[i], bf[j], acc[i][j], 0, 0, 0);
        }
    }

    // epilogue: D[row=quad*4+r][col=fl] per 16x16 tile
    float* Cf = (float*)Cp;
    unsigned short* Cb = (unsigned short*)Cp;
#pragma unroll
    for (int j = 0; j < 4; ++j) {
        const int c = nW + j * 16 + fl;
        const float bv = bias[c];
        const int cg = col0 + c;
#pragma unroll
        for (int i = 0; i < 4; ++i) {
            const int row0 = bm * 128 + mW + i * 16 + (quad << 2);
#pragma unroll
            for (int r = 0; r < 4; ++r) {
                const float v = acc[i][j][r] + bv;
                if (cbf) Cb[(size_t)(row0 + r) * ldc + cg] = f2bf(v);
                else     Cf[(size_t)(row0 + r) * ldc + cg] = v;
            }
        }
    }
}

// ---------------------------------------------------------------------------
// Sampling: 8 queries / 256-thread block, 32 thr/query (8 heads x 4 groups
// of 8 channels). ushort8 (16B) corner loads, packed bf16 unpack.
// ---------------------------------------------------------------------------
__global__ __launch_bounds__(256) void sample_k(
    const float* __restrict__ offattn,          // NQ x 384
    const unsigned short* __restrict__ values,  // (2*TOK) x 256 bf16 compact
    const float* __restrict__ qpos,             // NQ x 2
    const int*   __restrict__ qlevel,           // NQ
    unsigned short* __restrict__ qout)          // NQ x 256 bf16
{
    __shared__ float  sRow[8][384];
    __shared__ float4 sW[8][128];
    __shared__ int4   sIdx[8][128];

    const int tid = threadIdx.x;
    const int qbase = blockIdx.x << 3;

    {
        const float4* rb = (const float4*)(offattn + (size_t)qbase * 384);
        float4* sf = (float4*)sRow;
#pragma unroll
        for (int i = 0; i < 3; ++i) sf[tid + i * 256] = rb[tid + i * 256];
    }
    __syncthreads();

    if (tid < 64) {
        const int qn = tid >> 3, h = tid & 7;
        float m = -1e30f;
#pragma unroll
        for (int j = 0; j < 16; ++j) m = fmaxf(m, sRow[qn][256 + j * 8 + h]);
        float e[16], s = 0.f;
#pragma unroll
        for (int j = 0; j < 16; ++j) { e[j] = __expf(sRow[qn][256 + j * 8 + h] - m); s += e[j]; }
        float inv = 1.0f / s;
#pragma unroll
        for (int j = 0; j < 16; ++j) sRow[qn][256 + j * 8 + h] = e[j] * inv;
    }
    __syncthreads();

    const int LBASE[4] = {0, 4096, 5120, 5376};
#pragma unroll
    for (int ss = 0; ss < 4; ++ss) {
        const int s  = tid + ss * 256;
        const int qn = s >> 7;
        const int c  = s & 127;
        const int pl = c >> 3;
        const int l  = pl & 3;
        const int q  = qbase + qn;
        const int b  = (q >= TOK) ? 1 : 0;
        const float ph = qpos[2 * q], pw = qpos[2 * q + 1];
        const int ql = qlevel[q];
        const float invq = 1.0f / (float)(64 >> ql);
        const int Hl = 64 >> l;
        const float Hlf = (float)Hl;
        const float sc = invq * Hlf;
        float lh = ph * sc + sRow[qn][2 * c];
        float lw = pw * sc + sRow[qn][2 * c + 1];
        const float aw = sRow[qn][256 + c];
        lh = fminf(fmaxf(lh, 0.f), Hlf);
        lw = fminf(fmaxf(lw, 0.f), Hlf);
        const float fh0 = floorf(lh), fw0 = floorf(lw);
        const int h0 = (int)fh0, w0 = (int)fw0;
        const float fh = lh - fh0, fw = lw - fw0;
        float w00 = (1.f - fh) * (1.f - fw);
        float w01 = (1.f - fh) * fw;
        float w10 = fh * (1.f - fw);
        float w11 = fh * fw;
        if (h0     >= Hl) { w00 = 0.f; w01 = 0.f; }
        if (h0 + 1 >= Hl) { w10 = 0.f; w11 = 0.f; }
        if (w0     >= Hl) { w00 = 0.f; w10 = 0.f; }
        if (w0 + 1 >= Hl) { w01 = 0.f; w11 = 0.f; }
        const int h0c = min(h0, Hl - 1), h1c = min(h0 + 1, Hl - 1);
        const int w0c = min(w0, Hl - 1), w1c = min(w0 + 1, Hl - 1);
        const int base = b * TOK + LBASE[l];
        sW[qn][c]   = make_float4(aw * w00, aw * w01, aw * w10, aw * w11);
        sIdx[qn][c] = make_int4((base + h0c * Hl + w0c) << 8,
                                (base + h0c * Hl + w1c) << 8,
                                (base + h1c * Hl + w0c) << 8,
                                (base + h1c * Hl + w1c) << 8);
    }
    __syncthreads();

    const int qn = tid >> 5;
    const int t  = tid & 31;
    const int h  = t >> 2;
    const int dg = t & 3;
    const unsigned short* vb = values + h * 32 + (dg << 3);
    float a[8] = {};
#pragma unroll
    for (int pl = 0; pl < 16; ++pl) {
        const int c = pl * 8 + h;
        const float4 wt = sW[qn][c];
        const int4  id = sIdx[qn][c];
        const uint4 u00 = *(const uint4*)(vb + id.x);
        const uint4 u01 = *(const uint4*)(vb + id.y);
        const uint4 u10 = *(const uint4*)(vb + id.z);
        const uint4 u11 = *(const uint4*)(vb + id.w);
#define ACC8(U, W)                                         \
        a[0] = fmaf(W, bf2f_lo(U.x), a[0]);                \
        a[1] = fmaf(W, bf2f_hi(U.x), a[1]);                \
        a[2] = fmaf(W, bf2f_lo(U.y), a[2]);                \
        a[3] = fmaf(W, bf2f_hi(U.y), a[3]);                \
        a[4] = fmaf(W, bf2f_lo(U.z), a[4]);                \
        a[5] = fmaf(W, bf2f_hi(U.z), a[5]);                \
        a[6] = fmaf(W, bf2f_lo(U.w), a[6]);                \
        a[7] = fmaf(W, bf2f_hi(U.w), a[7]);
        ACC8(u00, wt.x)
        ACC8(u01, wt.y)
        ACC8(u10, wt.z)
        ACC8(u11, wt.w)
#undef ACC8
    }
    const int q = qbase + qn;
    uint4 o;
    o.x = pack2(a[0], a[1]);
    o.y = pack2(a[2], a[3]);
    o.z = pack2(a[4], a[5]);
    o.w = pack2(a[6], a[7]);
    *(uint4*)(qout + (size_t)q * 256 + h * 32 + (dg << 3)) = o;
}

// ---------------------------------------------------------------------------
extern "C" void kernel_launch(void* const* d_in, const int* in_sizes, int n_in,
                              void* d_out, int out_size, void* d_ws, size_t ws_size,
                              hipStream_t stream)
{
    const float* query  = (const float*)d_in[0];
    const float* qpos   = (const float*)d_in[1];
    const float* fm     = (const float*)d_in[3];
    const int*   qlvl   = (const int*)d_in[5];
    const float* W_off  = (const float*)d_in[6];
    const float* b_off  = (const float*)d_in[7];
    const float* W_attn = (const float*)d_in[8];
    const float* b_attn = (const float*)d_in[9];
    const float* W_val  = (const float*)d_in[10];
    const float* b_val  = (const float*)d_in[11];
    const float* W_out  = (const float*)d_in[12];
    const float* b_out  = (const float*)d_in[13];
    float* out = (float*)d_out;

    char* ws = (char*)d_ws;
    unsigned short* vsrc    = (unsigned short*)ws;                     // NQ*256 bf16
    unsigned short* qbf     = vsrc + (size_t)NQ * 256;                 // NQ*256 bf16
    unsigned short* WtAll   = qbf + (size_t)NQ * 256;                  // 896*256 bf16
    unsigned short* values  = WtAll + (size_t)896 * 256;               // NQ*256 bf16
    unsigned short* qout    = values + (size_t)NQ * 256;               // NQ*256 bf16
    float*          offattn = (float*)(qout + (size_t)NQ * 256);       // NQ*384 f32

    dim3 blk(256);
    prep_k<<<dim3(5496), blk, 0, stream>>>(query, fm, W_val, W_off, W_attn, W_out,
                                           qbf, vsrc, WtAll);
    gemm_bf16_k<<<dim3(85, 5), blk, 0, stream>>>(vsrc, qbf, WtAll,
                                                 b_val, b_off, b_attn,
                                                 values, offattn, 0);
    sample_k<<<dim3(NQ / 8), blk, 0, stream>>>(offattn, values, qpos, qlvl, qout);
    gemm_bf16_k<<<dim3(85, 2), blk, 0, stream>>>(qout, nullptr, WtAll,
                                                 b_out, nullptr, nullptr,
                                                 out, nullptr, 1);
}

// Round 5
// 156.303 us; speedup vs baseline: 1.7091x; 1.0102x over previous
//
#include <hip/hip_runtime.h>
#include <math.h>

#define NQ   10880
#define TOK  5440

typedef short s16x8 __attribute__((ext_vector_type(8)));
typedef float f32x4 __attribute__((ext_vector_type(4)));

__device__ __forceinline__ float bf2f_lo(unsigned int u) {
    return __uint_as_float(u << 16);
}
__device__ __forceinline__ float bf2f_hi(unsigned int u) {
    return __uint_as_float(u & 0xFFFF0000u);
}
__device__ __forceinline__ unsigned short f2bf(float f) {
    unsigned int u = __float_as_uint(f);
    u += 0x7FFFu + ((u >> 16) & 1u);
    return (unsigned short)(u >> 16);
}
__device__ __forceinline__ unsigned int pack2(float a, float b) {
    return (unsigned int)f2bf(a) | ((unsigned int)f2bf(b) << 16);
}

// ---------------------------------------------------------------------------
// prep: query->bf16 (qbf), gather fm->bf16 compact (vsrc),
//       transpose+convert weights -> WtAll[896][256] bf16
// ---------------------------------------------------------------------------
__global__ __launch_bounds__(256) void prep_k(
    const float* __restrict__ query, const float* __restrict__ fm,
    const float* __restrict__ W_val, const float* __restrict__ W_off,
    const float* __restrict__ W_attn, const float* __restrict__ W_out,
    unsigned short* __restrict__ qbf, unsigned short* __restrict__ vsrc,
    unsigned short* __restrict__ WtAll)
{
    const int blk = blockIdx.x;
    const int tid = threadIdx.x;

    if (blk < 2720) {
        const int lin4 = blk * 256 + tid;
        float4 f = *(const float4*)(query + (size_t)lin4 * 4);
        uint2 o;
        o.x = pack2(f.x, f.y);
        o.y = pack2(f.z, f.w);
        *(uint2*)(qbf + (size_t)lin4 * 4) = o;
    } else if (blk < 5440) {
        const int lin4 = (blk - 2720) * 256 + tid;
        const int r = lin4 >> 6;
        const int c4 = (lin4 & 63) << 2;
        const int b = (r >= TOK) ? 1 : 0;
        const int t = r - b * TOK;
        int l, hh, ww;
        if (t < 4096)      { l = 0; hh = t >> 6; ww = t & 63; }
        else if (t < 5120) { int i = t - 4096; l = 1; hh = i >> 5; ww = i & 31; }
        else if (t < 5376) { int i = t - 5120; l = 2; hh = i >> 4; ww = i & 15; }
        else               { int i = t - 5376; l = 3; hh = i >> 3; ww = i & 7; }
        const float* p = fm + ((size_t)((((b * 64 + hh) * 64 + ww) * 4) + l) << 8) + c4;
        float4 f = *(const float4*)p;
        uint2 o;
        o.x = pack2(f.x, f.y);
        o.y = pack2(f.z, f.w);
        *(uint2*)(vsrc + (size_t)r * 256 + c4) = o;
    } else {
        __shared__ unsigned short T[64][72];
        const int bt = blk - 5440;
        const int kt = bt & 3;
        const int ct = bt >> 2;
        const int c0 = ct * 64;
        const float* Wp; int ldw, cl0;
        if (c0 < 256)      { Wp = W_val;  ldw = 256; cl0 = c0; }
        else if (c0 < 512) { Wp = W_off;  ldw = 256; cl0 = c0 - 256; }
        else if (c0 < 640) { Wp = W_attn; ldw = 128; cl0 = c0 - 512; }
        else               { Wp = W_out;  ldw = 256; cl0 = c0 - 640; }

        const int kk = tid >> 2;
        const int cq = (tid & 3) << 4;
        const float* src = Wp + (size_t)(kt * 64 + kk) * ldw + cl0 + cq;
        float4 f0 = *(const float4*)(src);
        float4 f1 = *(const float4*)(src + 4);
        float4 f2 = *(const float4*)(src + 8);
        float4 f3 = *(const float4*)(src + 12);
        uint4 w0, w1;
        w0.x = pack2(f0.x, f0.y); w0.y = pack2(f0.z, f0.w);
        w0.z = pack2(f1.x, f1.y); w0.w = pack2(f1.z, f1.w);
        w1.x = pack2(f2.x, f2.y); w1.y = pack2(f2.z, f2.w);
        w1.z = pack2(f3.x, f3.y); w1.w = pack2(f3.z, f3.w);
        *(uint4*)&T[kk][cq]     = w0;
        *(uint4*)&T[kk][cq + 8] = w1;
        __syncthreads();
        const int cc = tid >> 2;
        const int kq = (tid & 3) << 4;
        union { unsigned short u[16]; uint4 q[2]; } ob;
#pragma unroll
        for (int j = 0; j < 16; ++j) ob.u[j] = T[kq + j][cc];
        unsigned short* dst = WtAll + (size_t)(c0 + cc) * 256 + kt * 64 + kq;
        *(uint4*)(dst)     = ob.q[0];
        *(uint4*)(dst + 8) = ob.q[1];
    }
}

// ---------------------------------------------------------------------------
// all-bf16 MFMA GEMM: BM=BN=128, BK=64, 4 waves, 64x64/wave (4x4 16x16x32).
// mode 0: bn 0,1 -> values(bf16) from vsrc; bn 2..4 -> offattn(f32) from qbf.
// mode 1: bn 0,1 -> out(f32) from qout (A1).
// ---------------------------------------------------------------------------
__global__ __launch_bounds__(256) void gemm_bf16_k(
    const unsigned short* __restrict__ A1, const unsigned short* __restrict__ A2,
    const unsigned short* __restrict__ Wt,
    const float* __restrict__ bias1, const float* __restrict__ bias2,
    const float* __restrict__ bias3,
    void* __restrict__ C1, void* __restrict__ C2, int mode)
{
    __shared__ unsigned short As[128][72];
    __shared__ unsigned short Bs[128][72];

    const int tid = threadIdx.x;
    const int bm = blockIdx.x, bn = blockIdx.y;

    const unsigned short* A;
    const float* bias;
    void* Cp; int ldc, col0, cbf, wr0;
    if (mode == 0) {
        if (bn < 2) {
            A = A1; wr0 = bn * 128; bias = bias1 + bn * 128;
            Cp = C1; ldc = 256; col0 = bn * 128; cbf = 1;
        } else {
            A = A2; wr0 = bn * 128;
            bias = (bn < 4) ? bias2 + (bn - 2) * 128 : bias3;
            Cp = C2; ldc = 384; col0 = (bn - 2) * 128; cbf = 0;
        }
    } else {
        A = A1; wr0 = 640 + bn * 128; bias = bias1 + bn * 128;
        Cp = C1; ldc = 256; col0 = bn * 128; cbf = 0;
    }

    const int sr  = tid >> 1;
    const int skc = (tid & 1) << 5;
    const unsigned short* Ap = A  + (size_t)(bm * 128 + sr) * 256 + skc;
    const unsigned short* Bp = Wt + (size_t)(wr0 + sr) * 256 + skc;

    const int w = tid >> 6, lane = tid & 63;
    const int quad = lane >> 4, fl = lane & 15;
    const int quad8 = quad << 3;
    const int mW = (w >> 1) << 6, nW = (w & 1) << 6;

    f32x4 acc[4][4] = {};

    for (int k0 = 0; k0 < 256; k0 += 64) {
        uint4 av0 = *(const uint4*)(Ap + k0);
        uint4 av1 = *(const uint4*)(Ap + k0 + 8);
        uint4 av2 = *(const uint4*)(Ap + k0 + 16);
        uint4 av3 = *(const uint4*)(Ap + k0 + 24);
        uint4 bv0 = *(const uint4*)(Bp + k0);
        uint4 bv1 = *(const uint4*)(Bp + k0 + 8);
        uint4 bv2 = *(const uint4*)(Bp + k0 + 16);
        uint4 bv3 = *(const uint4*)(Bp + k0 + 24);
        __syncthreads();
        *(uint4*)&As[sr][skc]      = av0;
        *(uint4*)&As[sr][skc + 8]  = av1;
        *(uint4*)&As[sr][skc + 16] = av2;
        *(uint4*)&As[sr][skc + 24] = av3;
        *(uint4*)&Bs[sr][skc]      = bv0;
        *(uint4*)&Bs[sr][skc + 8]  = bv1;
        *(uint4*)&Bs[sr][skc + 16] = bv2;
        *(uint4*)&Bs[sr][skc + 24] = bv3;
        __syncthreads();
#pragma unroll
        for (int ks = 0; ks < 64; ks += 32) {
            s16x8 af[4], bf[4];
#pragma unroll
            for (int i = 0; i < 4; ++i) {
                af[i] = *(const s16x8*)&As[mW + i * 16 + fl][ks + quad8];
                bf[i] = *(const s16x8*)&Bs[nW + i * 16 + fl][ks + quad8];
            }
#pragma unroll
            for (int i = 0; i < 4; ++i)
#pragma unroll
                for (int j = 0; j < 4; ++j)
                    acc[i][j] = __builtin_amdgcn_mfma_f32_16x16x32_bf16(
                        af[i], bf[j], acc[i][j], 0, 0, 0);
        }
    }

    float* Cf = (float*)Cp;
    unsigned short* Cb = (unsigned short*)Cp;
#pragma unroll
    for (int j = 0; j < 4; ++j) {
        const int c = nW + j * 16 + fl;
        const float bv = bias[c];
        const int cg = col0 + c;
#pragma unroll
        for (int i = 0; i < 4; ++i) {
            const int row0 = bm * 128 + mW + i * 16 + (quad << 2);
#pragma unroll
            for (int r = 0; r < 4; ++r) {
                const float v = acc[i][j][r] + bv;
                if (cbf) Cb[(size_t)(row0 + r) * ldc + cg] = f2bf(v);
                else     Cf[(size_t)(row0 + r) * ldc + cg] = v;
            }
        }
    }
}

// ---------------------------------------------------------------------------
// Sampling: 8 queries / 256-thread block, 32 thr/query.
// XCD-band swizzle: band = blockIdx.x & 7 selects a horizontal band of the
// normalized-y axis (level-l rows [band*8H_l/64, ...)). With round-robin
// workgroup->XCD mapping, each XCD's L2 working set is ~1 MB (fits 4 MB L2)
// instead of thrashing the full 5.5 MB `values`.
// Band segment sizes per batch: l0=512, l1=128, l2=32, l3=8 (all /8) -> 85
// blocks per batch per band, queries contiguous within a block.
// ---------------------------------------------------------------------------
__global__ __launch_bounds__(256) void sample_k(
    const float* __restrict__ offattn,          // NQ x 384
    const unsigned short* __restrict__ values,  // (2*TOK) x 256 bf16 compact
    const float* __restrict__ qpos,             // NQ x 2
    const int*   __restrict__ qlevel,           // NQ
    unsigned short* __restrict__ qout)          // NQ x 256 bf16
{
    __shared__ float  sRow[8][384];
    __shared__ float4 sW[8][128];
    __shared__ int4   sIdx[8][128];

    const int tid = threadIdx.x;

    // band permutation: blockIdx.x = band + 8*(bat*85 + i0/8)
    const int band = blockIdx.x & 7;
    const int g    = blockIdx.x >> 3;       // 0..169
    const int bat  = g / 85;
    const int i0   = (g % 85) << 3;         // 0..672, step 8
    int qs;
    if (i0 < 512)      qs = band * 512 + i0;
    else if (i0 < 640) qs = 4096 + band * 128 + (i0 - 512);
    else if (i0 < 672) qs = 5120 + band * 32 + (i0 - 640);
    else               qs = 5376 + band * 8;
    const int qbase = bat * TOK + qs;

    {
        const float4* rb = (const float4*)(offattn + (size_t)qbase * 384);
        float4* sf = (float4*)sRow;
#pragma unroll
        for (int i = 0; i < 3; ++i) sf[tid + i * 256] = rb[tid + i * 256];
    }
    __syncthreads();

    if (tid < 64) {
        const int qn = tid >> 3, h = tid & 7;
        float m = -1e30f;
#pragma unroll
        for (int j = 0; j < 16; ++j) m = fmaxf(m, sRow[qn][256 + j * 8 + h]);
        float e[16], s = 0.f;
#pragma unroll
        for (int j = 0; j < 16; ++j) { e[j] = __expf(sRow[qn][256 + j * 8 + h] - m); s += e[j]; }
        float inv = 1.0f / s;
#pragma unroll
        for (int j = 0; j < 16; ++j) sRow[qn][256 + j * 8 + h] = e[j] * inv;
    }
    __syncthreads();

    const int LBASE[4] = {0, 4096, 5120, 5376};
#pragma unroll
    for (int ss = 0; ss < 4; ++ss) {
        const int s  = tid + ss * 256;
        const int qn = s >> 7;
        const int c  = s & 127;
        const int pl = c >> 3;
        const int l  = pl & 3;
        const int q  = qbase + qn;
        const int b  = (q >= TOK) ? 1 : 0;
        const float ph = qpos[2 * q], pw = qpos[2 * q + 1];
        const int ql = qlevel[q];
        const float invq = 1.0f / (float)(64 >> ql);
        const int Hl = 64 >> l;
        const float Hlf = (float)Hl;
        const float sc = invq * Hlf;
        float lh = ph * sc + sRow[qn][2 * c];
        float lw = pw * sc + sRow[qn][2 * c + 1];
        const float aw = sRow[qn][256 + c];
        lh = fminf(fmaxf(lh, 0.f), Hlf);
        lw = fminf(fmaxf(lw, 0.f), Hlf);
        const float fh0 = floorf(lh), fw0 = floorf(lw);
        const int h0 = (int)fh0, w0 = (int)fw0;
        const float fh = lh - fh0, fw = lw - fw0;
        float w00 = (1.f - fh) * (1.f - fw);
        float w01 = (1.f - fh) * fw;
        float w10 = fh * (1.f - fw);
        float w11 = fh * fw;
        if (h0     >= Hl) { w00 = 0.f; w01 = 0.f; }
        if (h0 + 1 >= Hl) { w10 = 0.f; w11 = 0.f; }
        if (w0     >= Hl) { w00 = 0.f; w10 = 0.f; }
        if (w0 + 1 >= Hl) { w01 = 0.f; w11 = 0.f; }
        const int h0c = min(h0, Hl - 1), h1c = min(h0 + 1, Hl - 1);
        const int w0c = min(w0, Hl - 1), w1c = min(w0 + 1, Hl - 1);
        const int base = b * TOK + LBASE[l];
        sW[qn][c]   = make_float4(aw * w00, aw * w01, aw * w10, aw * w11);
        sIdx[qn][c] = make_int4((base + h0c * Hl + w0c) << 8,
                                (base + h0c * Hl + w1c) << 8,
                                (base + h1c * Hl + w0c) << 8,
                                (base + h1c * Hl + w1c) << 8);
    }
    __syncthreads();

    const int qn = tid >> 5;
    const int t  = tid & 31;
    const int h  = t >> 2;
    const int dg = t & 3;
    const unsigned short* vb = values + h * 32 + (dg << 3);
    float a[8] = {};
#pragma unroll
    for (int pl = 0; pl < 16; ++pl) {
        const int c = pl * 8 + h;
        const float4 wt = sW[qn][c];
        const int4  id = sIdx[qn][c];
        const uint4 u00 = *(const uint4*)(vb + id.x);
        const uint4 u01 = *(const uint4*)(vb + id.y);
        const uint4 u10 = *(const uint4*)(vb + id.z);
        const uint4 u11 = *(const uint4*)(vb + id.w);
#define ACC8(U, W)                                         \
        a[0] = fmaf(W, bf2f_lo(U.x), a[0]);                \
        a[1] = fmaf(W, bf2f_hi(U.x), a[1]);                \
        a[2] = fmaf(W, bf2f_lo(U.y), a[2]);                \
        a[3] = fmaf(W, bf2f_hi(U.y), a[3]);                \
        a[4] = fmaf(W, bf2f_lo(U.z), a[4]);                \
        a[5] = fmaf(W, bf2f_hi(U.z), a[5]);                \
        a[6] = fmaf(W, bf2f_lo(U.w), a[6]);                \
        a[7] = fmaf(W, bf2f_hi(U.w), a[7]);
        ACC8(u00, wt.x)
        ACC8(u01, wt.y)
        ACC8(u10, wt.z)
        ACC8(u11, wt.w)
#undef ACC8
    }
    const int q = qbase + qn;
    uint4 o;
    o.x = pack2(a[0], a[1]);
    o.y = pack2(a[2], a[3]);
    o.z = pack2(a[4], a[5]);
    o.w = pack2(a[6], a[7]);
    *(uint4*)(qout + (size_t)q * 256 + h * 32 + (dg << 3)) = o;
}

// ---------------------------------------------------------------------------
extern "C" void kernel_launch(void* const* d_in, const int* in_sizes, int n_in,
                              void* d_out, int out_size, void* d_ws, size_t ws_size,
                              hipStream_t stream)
{
    const float* query  = (const float*)d_in[0];
    const float* qpos   = (const float*)d_in[1];
    const float* fm     = (const float*)d_in[3];
    const int*   qlvl   = (const int*)d_in[5];
    const float* W_off  = (const float*)d_in[6];
    const float* b_off  = (const float*)d_in[7];
    const float* W_attn = (const float*)d_in[8];
    const float* b_attn = (const float*)d_in[9];
    const float* W_val  = (const float*)d_in[10];
    const float* b_val  = (const float*)d_in[11];
    const float* W_out  = (const float*)d_in[12];
    const float* b_out  = (const float*)d_in[13];
    float* out = (float*)d_out;

    char* ws = (char*)d_ws;
    unsigned short* vsrc    = (unsigned short*)ws;                     // NQ*256 bf16
    unsigned short* qbf     = vsrc + (size_t)NQ * 256;                 // NQ*256 bf16
    unsigned short* WtAll   = qbf + (size_t)NQ * 256;                  // 896*256 bf16
    unsigned short* values  = WtAll + (size_t)896 * 256;               // NQ*256 bf16
    unsigned short* qout    = values + (size_t)NQ * 256;               // NQ*256 bf16
    float*          offattn = (float*)(qout + (size_t)NQ * 256);       // NQ*384 f32

    dim3 blk(256);
    prep_k<<<dim3(5496), blk, 0, stream>>>(query, fm, W_val, W_off, W_attn, W_out,
                                           qbf, vsrc, WtAll);
    gemm_bf16_k<<<dim3(85, 5), blk, 0, stream>>>(vsrc, qbf, WtAll,
                                                 b_val, b_off, b_attn,
                                                 values, offattn, 0);
    sample_k<<<dim3(NQ / 8), blk, 0, stream>>>(offattn, values, qpos, qlvl, qout);
    gemm_bf16_k<<<dim3(85, 2), blk, 0, stream>>>(qout, nullptr, WtAll,
                                                 b_out, nullptr, nullptr,
                                                 out, nullptr, 1);
}